// Round 8
// baseline (419.640 us; speedup 1.0000x reference)
//
#include <hip/hip_runtime.h>
#include <hip/hip_fp16.h>

// ---------------------------------------------------------------------------
// ReconGNN: out = conv(relu(conv(x@W1^T)+b1) @ W2^T) + b2
// R8: (a) conv64+b1/relu+gemm2+dis-prescale fused into k_fuse (gemm2 was a
// separate 12.8MB-in/8MB-out pass; aggregation and the 64->40 map are both
// per-node, so the wave finishes its node then applies W2^T from LDS).
// (b) h2 written padded (stride 64 halves, feature halves at byte 0/64) and
// conv40 runs 2 blocks/node-group with half=blockIdx&1 -> even/odd XCD
// parity shards the 6.4MB half-working-sets, aligned single-line gathers.
// Pipeline: memset -> detect -> binfill -> binscan -> degscat ->
//           gemm1_mfma -> k_fuse -> conv40(+b2, fp32 out)
// Aliases: binbuf==h1 (dead before gemm1 writes h1); h2pad lives in h1b.
// ---------------------------------------------------------------------------

typedef __attribute__((ext_vector_type(8))) _Float16 half8v;
typedef __attribute__((ext_vector_type(4))) float   float4v;

// ---- edge dtype detection: int64 edges read as int32 have all-zero odd words
__global__ void k_detect(const int* __restrict__ ed, int* __restrict__ flag, int nwords) {
  __shared__ int any;
  if (threadIdx.x == 0) any = 0;
  __syncthreads();
  #pragma unroll
  for (int u = 0; u < 8; ++u) {
    int idx = 2 * (threadIdx.x * 8 + u) + 1;
    if (idx < nwords && ed[idx] != 0) any = 1;
  }
  __syncthreads();
  if (threadIdx.x == 0) *flag = any ? 0 : 1;   // 1 => int64 layout
}

// ---- bucket edges by destination bin (c>>8), coalesced run writes ----
// record = r | (c&255)<<17   (N <= 131072)
__global__ void k_binfill(const int* __restrict__ ed, const int* __restrict__ flag,
                          int* __restrict__ gbincnt, unsigned* __restrict__ binbuf,
                          int E, int cap) {
  __shared__ int hist[512];
  __shared__ int cursor[512];
  int t = threadIdx.x;
  hist[t] = 0; hist[t + 256] = 0;
  __syncthreads();
  const int is64 = *flag;
  const int base = blockIdx.x * 8192;
  const int nE = min(8192, E - base);
  for (int j = t; j < nE; j += 256) {
    int e = base + j;
    int c = is64 ? ed[2 * (E + e)] : ed[E + e];
    atomicAdd(&hist[c >> 8], 1);
  }
  __syncthreads();
  for (int b = t; b < 512; b += 256) {
    int h = hist[b];
    cursor[b] = h ? atomicAdd(&gbincnt[b], h) : 0;
  }
  __syncthreads();
  for (int j = t; j < nE; j += 256) {
    int e = base + j;
    int r = is64 ? ed[2 * e] : ed[e];
    int c = is64 ? ed[2 * (E + e)] : ed[E + e];
    int bin = c >> 8;
    int pos = atomicAdd(&cursor[bin], 1);
    if (pos < cap)
      binbuf[(size_t)bin * cap + pos] = (unsigned)r | ((unsigned)(c & 255) << 17);
  }
}

// ---- single-block exclusive scan over clamped bin counts -> gbase ----
__global__ void k_binscan(const int* __restrict__ gbincnt, int* __restrict__ gbase,
                          int* __restrict__ rowptr, int NBINS, int N, int cap) {
  __shared__ int sd[512];
  int t = threadIdx.x;
  #pragma unroll
  for (int u = 0; u < 2; ++u) {
    int i = t + 256 * u;
    sd[i] = (i < NBINS) ? min(gbincnt[i], cap) : 0;
  }
  __syncthreads();
  for (int off = 1; off < 512; off <<= 1) {
    int v0 = (t >= off) ? sd[t - off] : 0;
    int i1 = t + 256;
    int v1 = sd[i1 - off];
    __syncthreads();
    sd[t] += v0; sd[i1] += v1;
    __syncthreads();
  }
  #pragma unroll
  for (int u = 0; u < 2; ++u) {
    int i = t + 256 * u;
    if (i < NBINS) gbase[i] = (i == 0) ? 0 : sd[i - 1];
  }
  if (t == 0) rowptr[N] = sd[NBINS - 1];
}

// ---- fused: per-bin degree + scan -> dis/rowptr, then scatter srcs ----
__global__ void k_degscat(const unsigned* __restrict__ binbuf, const int* __restrict__ gbincnt,
                          const int* __restrict__ gbase, float* __restrict__ dis,
                          int* __restrict__ rowptr, int* __restrict__ srcs, int N, int cap) {
  __shared__ int cnt[256];
  __shared__ int sd[256];
  __shared__ int cursor[256];
  int t = threadIdx.x, b = blockIdx.x;
  cnt[t] = 0;
  __syncthreads();
  int n = min(gbincnt[b], cap);
  const unsigned* buf = binbuf + (size_t)b * cap;
  for (int j = t; j < n; j += 256) atomicAdd(&cnt[buf[j] >> 17], 1);
  __syncthreads();
  sd[t] = cnt[t];
  __syncthreads();
  for (int off = 1; off < 256; off <<= 1) {
    int v = (t >= off) ? sd[t - off] : 0;
    __syncthreads();
    sd[t] += v;
    __syncthreads();
  }
  int rp = gbase[b] + ((t == 0) ? 0 : sd[t - 1]);
  cursor[t] = rp;
  int node = b * 256 + t;
  if (node < N) {
    int d = cnt[t];
    dis[node] = (d > 0) ? rsqrtf((float)d) : 0.f;
    rowptr[node] = rp;
  }
  __syncthreads();
  for (int j = t; j < n; j += 256) {
    unsigned rec = buf[j];
    int pos = atomicAdd(&cursor[rec >> 17], 1);
    srcs[pos] = (int)(rec & 0x1FFFF);
  }
}

// ---- gemm1 (MFMA f16): Y[N][64] = (X[N][128] @ W[64][128]^T) * dis, fp16 out
__launch_bounds__(256)
__global__ void k_gemm1_mfma(const float* __restrict__ X, const float* __restrict__ W,
                             const float* __restrict__ dis, __half* __restrict__ Y, int N) {
  __shared__ _Float16 xl[128 * 128];   // 32 KB
  __shared__ _Float16 wl[64 * 128];    // 16 KB
  const int t = threadIdx.x;
  const int row0 = blockIdx.x * 128;

  {
    int n = t >> 2, kb = (t & 3) * 32;
    const float* src = W + n * 128 + kb;
    #pragma unroll
    for (int j = 0; j < 4; ++j) {
      float4 va = *(const float4*)&src[j * 8];
      float4 vb = *(const float4*)&src[j * 8 + 4];
      _Float16 h8[8] = {(_Float16)va.x, (_Float16)va.y, (_Float16)va.z, (_Float16)va.w,
                        (_Float16)vb.x, (_Float16)vb.y, (_Float16)vb.z, (_Float16)vb.w};
      int k = kb + j * 8;
      *(float4*)&wl[n * 128 + (k ^ ((n & 7) * 8))] = *(float4*)h8;
    }
  }
  {
    int r = t >> 1, kb = (t & 1) * 64;
    int row = row0 + r;
    #pragma unroll
    for (int j = 0; j < 8; ++j) {
      float4 va = make_float4(0.f, 0.f, 0.f, 0.f), vb = va;
      if (row < N) {
        va = *(const float4*)&X[(size_t)row * 128 + kb + j * 8];
        vb = *(const float4*)&X[(size_t)row * 128 + kb + j * 8 + 4];
      }
      _Float16 h8[8] = {(_Float16)va.x, (_Float16)va.y, (_Float16)va.z, (_Float16)va.w,
                        (_Float16)vb.x, (_Float16)vb.y, (_Float16)vb.z, (_Float16)vb.w};
      int k = kb + j * 8;
      *(float4*)&xl[r * 128 + (k ^ ((r & 7) * 8))] = *(float4*)h8;
    }
  }
  __syncthreads();

  const int w = t >> 6, l = t & 63;
  const int m0 = w * 32;
  const int lr = l & 15, q = l >> 4;

  float4v acc[2][4] = {};
  #pragma unroll
  for (int kc = 0; kc < 4; ++kc) {
    half8v a[2], b[4];
    #pragma unroll
    for (int mt = 0; mt < 2; ++mt) {
      int m = m0 + mt * 16 + lr;
      int k = (kc * 32 + q * 8) ^ ((m & 7) * 8);
      a[mt] = *(half8v*)&xl[m * 128 + k];
    }
    #pragma unroll
    for (int nt = 0; nt < 4; ++nt) {
      int n = nt * 16 + lr;
      int k = (kc * 32 + q * 8) ^ ((n & 7) * 8);
      b[nt] = *(half8v*)&wl[n * 128 + k];
    }
    #pragma unroll
    for (int mt = 0; mt < 2; ++mt)
      #pragma unroll
      for (int nt = 0; nt < 4; ++nt)
        acc[mt][nt] = __builtin_amdgcn_mfma_f32_16x16x32_f16(a[mt], b[nt], acc[mt][nt], 0, 0, 0);
  }

  #pragma unroll
  for (int mt = 0; mt < 2; ++mt) {
    #pragma unroll
    for (int r = 0; r < 4; ++r) {
      int row = row0 + m0 + mt * 16 + q * 4 + r;
      if (row < N) {
        float dr = dis[row];
        #pragma unroll
        for (int nt = 0; nt < 4; ++nt)
          Y[(size_t)row * 64 + nt * 16 + lr] = __float2half_rn(acc[mt][nt][r] * dr);
      }
    }
  }
}

// ---- fused conv64(relu+b1) + gemm2 + dis prescale -> padded h2 ----
// Wave per node: predicated batch-8 gather of h1 (R7 conv64 loop), combine,
// v[64] -> LDS, then lanes 0..19 compute feature pairs via W2^T (LDS, fp32),
// write h2 padded: half0 features 0..19 at halves [0,20), half1 at [32,52).
__launch_bounds__(256)
__global__ void k_fuse(const __half* __restrict__ H, const int* __restrict__ rowptr,
                       const int* __restrict__ srcs, const float* __restrict__ dis,
                       const float* __restrict__ b1, const float* __restrict__ W2,
                       __half* __restrict__ h2, int N) {
  __shared__ float w2t[64 * 40];   // w2t[k*40+c] = W2[c*64+k], 10 KB
  __shared__ float vlds[4][64];    // per-wave node vector
  const int t = threadIdx.x;
  for (int i = t; i < 2560; i += 256) {
    int c = i >> 6, k = i & 63;
    w2t[k * 40 + c] = W2[i];
  }
  __syncthreads();

  const int w = t >> 6;
  int node = blockIdx.x * 4 + w;
  if (node < N) {
    int lane = t & 63;
    int sub = lane & 31, hf = lane >> 5;
    int s = rowptr[node], e = rowptr[node + 1];
    int last = e - 1;
    float ax = 0.f, ay = 0.f;
    for (int p = s + hf; p < e; p += 16) {
      int si[8];
      #pragma unroll
      for (int u = 0; u < 8; ++u) si[u] = srcs[min(p + 2 * u, last)];
      #pragma unroll
      for (int u = 0; u < 8; ++u) {
        float2 f = __half22float2(*(const __half2*)&H[(size_t)si[u] * 64 + 2 * sub]);
        if (p + 2 * u < e) { ax += f.x; ay += f.y; }
      }
    }
    ax += __shfl_xor(ax, 32);
    ay += __shfl_xor(ay, 32);
    float dn = dis[node];
    if (hf == 0) {   // v[k] = relu(agg*dis + b1[k]) -> LDS (wave-private slice)
      float vx = fmaxf(fmaf(ax, dn, b1[2 * sub]), 0.f);
      float vy = fmaxf(fmaf(ay, dn, b1[2 * sub + 1]), 0.f);
      vlds[w][2 * sub] = vx;
      vlds[w][2 * sub + 1] = vy;
    }
    // same-wave LDS producer->consumer: in-order per wave, no barrier needed
    int j = t & 63;
    if (j < 20) {    // feature pair (2j, 2j+1)
      float d0 = 0.f, d1 = 0.f;
      #pragma unroll 8
      for (int k = 0; k < 64; ++k) {
        float vk = vlds[w][k];                       // broadcast
        float2 wv = *(const float2*)&w2t[k * 40 + 2 * j];
        d0 = fmaf(vk, wv.x, d0);
        d1 = fmaf(vk, wv.y, d1);
      }
      int off = (j < 10) ? 2 * j : (12 + 2 * j);     // halves: [0,20) and [32,52)
      *(__half2*)&h2[(size_t)node * 64 + off] = __floats2half2_rn(d0 * dn, d1 * dn);
    }
  }
}

// ---- conv2 (D=40, fp32 out): feature-half per block (XCD parity), batch-8 --
__launch_bounds__(256)
__global__ void k_conv40(const __half* __restrict__ H, const int* __restrict__ rowptr,
                         const int* __restrict__ srcs, const float* __restrict__ dis,
                         const float* __restrict__ bias, float* __restrict__ out, int N) {
  int half = blockIdx.x & 1;             // even/odd blockIdx -> even/odd XCD
  int node = (blockIdx.x >> 1) * 4 + (threadIdx.x >> 6);
  if (node >= N) return;
  int lane = threadIdx.x & 63;
  int sub = lane & 31, hf = lane >> 5;
  bool act = sub < 10;                   // 10 half2 lanes cover 20 features
  int s = rowptr[node], e = rowptr[node + 1];
  int last = e - 1;
  int base = half * 32 + 2 * sub;        // padded h2: halves at 0 and 32
  float ax = 0.f, ay = 0.f;
  for (int p = s + hf; p < e; p += 16) {
    int si[8];
    #pragma unroll
    for (int u = 0; u < 8; ++u) si[u] = srcs[min(p + 2 * u, last)];
    #pragma unroll
    for (int u = 0; u < 8; ++u) {
      if (act) {
        float2 f = __half22float2(*(const __half2*)&H[(size_t)si[u] * 64 + base]);
        if (p + 2 * u < e) { ax += f.x; ay += f.y; }
      }
    }
  }
  ax += __shfl_xor(ax, 32);
  ay += __shfl_xor(ay, 32);
  if (hf == 0 && act) {
    float dn = dis[node];
    int f = half * 20 + 2 * sub;         // feature index
    float2 v = make_float2(fmaf(ax, dn, bias[f]), fmaf(ay, dn, bias[f + 1]));
    *(float2*)&out[(size_t)node * 40 + f] = v;
  }
}

extern "C" void kernel_launch(void* const* d_in, const int* in_sizes, int n_in,
                              void* d_out, int out_size, void* d_ws, size_t ws_size,
                              hipStream_t stream) {
  const float* x  = (const float*)d_in[0];
  const int*   ed = (const int*)d_in[1];
  const float* W1 = (const float*)d_in[2];
  const float* b1 = (const float*)d_in[3];
  const float* W2 = (const float*)d_in[4];
  const float* b2 = (const float*)d_in[5];
  float* out = (float*)d_out;

  const int FIN = 128, FH = 64, FO = 40;
  const int N = in_sizes[0] / FIN;
  const int E = in_sizes[1] / 2;
  const int NBINS = (N + 255) >> 8;              // 391

  char* ws = (char*)d_ws;
  size_t off = 0;
  auto alloc = [&](size_t bytes) {
    void* p = ws + off;
    off = (off + bytes + 255) & ~(size_t)255;
    return p;
  };
  int*    flag    = (int*)alloc(4);
  int*    gbincnt = (int*)alloc(512 * 4);
  int*    gbase   = (int*)alloc(512 * 4);
  float*  dis     = (float*)alloc((size_t)N * 4);
  int*    rowptr  = (int*)alloc(((size_t)N + 1) * 4);
  int*    srcs    = (int*)alloc((size_t)E * 4);
  __half* h1      = (__half*)alloc((size_t)N * FH * 2);   // gemm1 out; aliases binbuf
  __half* h2pad   = (__half*)alloc((size_t)N * 64 * 2);   // fused out, stride 64
  int cap = (int)(((size_t)N * FH * 2) / ((size_t)NBINS * 4));
  if (cap > 8192) cap = 8192;                    // mean bin load ~4092
  unsigned* binbuf = (unsigned*)h1;

  hipMemsetAsync(gbincnt, 0, 512 * 4, stream);
  k_detect<<<1, 256, 0, stream>>>(ed, flag, in_sizes[1]);

  int fb = (E + 8191) / 8192;
  k_binfill<<<fb, 256, 0, stream>>>(ed, flag, gbincnt, binbuf, E, cap);
  k_binscan<<<1, 256, 0, stream>>>(gbincnt, gbase, rowptr, NBINS, N, cap);
  k_degscat<<<NBINS, 256, 0, stream>>>(binbuf, gbincnt, gbase, dis, rowptr, srcs, N, cap);

  int mb = (N + 127) / 128;
  int cb = (N + 3) / 4;
  k_gemm1_mfma<<<mb, 256, 0, stream>>>(x, W1, dis, h1, N);
  k_fuse<<<cb, 256, 0, stream>>>(h1, rowptr, srcs, dis, b1, W2, h2pad, N);
  k_conv40<<<cb * 2, 256, 0, stream>>>(h2pad, rowptr, srcs, dis, b2, out, N);
}

// Round 9
// 365.162 us; speedup vs baseline: 1.1492x; 1.1492x over previous
//
#include <hip/hip_runtime.h>
#include <hip/hip_fp16.h>

// ---------------------------------------------------------------------------
// ReconGNN: out = conv(relu(conv(x@W1^T)+b1) @ W2^T) + b2
// R9: revert R8's fusion+padding (regressed: padded h2 doubled line-touches
// and neither 6.4MB half fit a 4MB XCD-L2). R7 pipeline, plus:
//  (a) gemm2 writes two COMPACT half-feature arrays h2a/h2b (N x 20 fp16,
//      4.0MB each); conv2 runs as two SEQUENTIAL passes, each pass's random
//      gather set fits one XCD L2 -> misses ~= 8 XCD x 4MB compulsory.
//  (b) binfill caches packed records in LDS (kills 2nd 25.6MB read of ed).
//  (c) degscat caches bin records in LDS (kills 2nd 6.4MB binbuf read).
// Pipeline: memset -> detect -> binfill -> binscan -> degscat ->
//   gemm1_mfma -> conv64(relu+b1) -> gemm2(->h2a,h2b) -> conv20 x2
// Aliases: binbuf==h1 (dead before gemm1 writes h1).
// ---------------------------------------------------------------------------

typedef __attribute__((ext_vector_type(8))) _Float16 half8v;
typedef __attribute__((ext_vector_type(4))) float   float4v;

// ---- edge dtype detection: int64 edges read as int32 have all-zero odd words
__global__ void k_detect(const int* __restrict__ ed, int* __restrict__ flag, int nwords) {
  __shared__ int any;
  if (threadIdx.x == 0) any = 0;
  __syncthreads();
  #pragma unroll
  for (int u = 0; u < 8; ++u) {
    int idx = 2 * (threadIdx.x * 8 + u) + 1;
    if (idx < nwords && ed[idx] != 0) any = 1;
  }
  __syncthreads();
  if (threadIdx.x == 0) *flag = any ? 0 : 1;   // 1 => int64 layout
}

// ---- bucket edges by destination bin (c>>8); records cached in LDS ----
// record = r | (c&255)<<17   (N <= 131072)
__global__ void k_binfill(const int* __restrict__ ed, const int* __restrict__ flag,
                          int* __restrict__ gbincnt, unsigned* __restrict__ binbuf,
                          int E, int cap) {
  __shared__ int hist[512];
  __shared__ int cursor[512];
  __shared__ unsigned rec[4096];     // 16 KB
  __shared__ unsigned short binv[4096];  // 8 KB
  int t = threadIdx.x;
  hist[t] = 0; hist[t + 256] = 0;
  __syncthreads();
  const int is64 = *flag;
  const int base = blockIdx.x * 4096;
  const int nE = min(4096, E - base);
  // phase 1: read edges ONCE, pack to LDS, block-local histogram
  for (int j = t; j < nE; j += 256) {
    int e = base + j;
    int r = is64 ? ed[2 * e] : ed[e];
    int c = is64 ? ed[2 * (E + e)] : ed[E + e];
    rec[j] = (unsigned)r | ((unsigned)(c & 255) << 17);
    binv[j] = (unsigned short)(c >> 8);
    atomicAdd(&hist[c >> 8], 1);
  }
  __syncthreads();
  // phase 2: reserve contiguous global runs
  for (int b = t; b < 512; b += 256) {
    int h = hist[b];
    cursor[b] = h ? atomicAdd(&gbincnt[b], h) : 0;
  }
  __syncthreads();
  // phase 3: scatter from LDS (order within bin irrelevant)
  for (int j = t; j < nE; j += 256) {
    int bin = binv[j];
    int pos = atomicAdd(&cursor[bin], 1);
    if (pos < cap)
      binbuf[(size_t)bin * cap + pos] = rec[j];
  }
}

// ---- single-block exclusive scan over clamped bin counts -> gbase ----
__global__ void k_binscan(const int* __restrict__ gbincnt, int* __restrict__ gbase,
                          int* __restrict__ rowptr, int NBINS, int N, int cap) {
  __shared__ int sd[512];
  int t = threadIdx.x;
  #pragma unroll
  for (int u = 0; u < 2; ++u) {
    int i = t + 256 * u;
    sd[i] = (i < NBINS) ? min(gbincnt[i], cap) : 0;
  }
  __syncthreads();
  for (int off = 1; off < 512; off <<= 1) {
    int v0 = (t >= off) ? sd[t - off] : 0;
    int i1 = t + 256;
    int v1 = sd[i1 - off];
    __syncthreads();
    sd[t] += v0; sd[i1] += v1;
    __syncthreads();
  }
  #pragma unroll
  for (int u = 0; u < 2; ++u) {
    int i = t + 256 * u;
    if (i < NBINS) gbase[i] = (i == 0) ? 0 : sd[i - 1];
  }
  if (t == 0) rowptr[N] = sd[NBINS - 1];
}

// ---- fused: per-bin degree + scan -> dis/rowptr, then scatter srcs ----
// bin records cached in LDS (<= cap <= 8192)
__global__ void k_degscat(const unsigned* __restrict__ binbuf, const int* __restrict__ gbincnt,
                          const int* __restrict__ gbase, float* __restrict__ dis,
                          int* __restrict__ rowptr, int* __restrict__ srcs, int N, int cap) {
  __shared__ int cnt[256];
  __shared__ int sd[256];
  __shared__ int cursor[256];
  __shared__ unsigned rec[8192];   // 32 KB
  int t = threadIdx.x, b = blockIdx.x;
  cnt[t] = 0;
  __syncthreads();
  int n = min(gbincnt[b], cap);
  const unsigned* buf = binbuf + (size_t)b * cap;
  for (int j = t; j < n; j += 256) {
    unsigned v = buf[j];
    rec[j] = v;
    atomicAdd(&cnt[v >> 17], 1);
  }
  __syncthreads();
  sd[t] = cnt[t];
  __syncthreads();
  for (int off = 1; off < 256; off <<= 1) {
    int v = (t >= off) ? sd[t - off] : 0;
    __syncthreads();
    sd[t] += v;
    __syncthreads();
  }
  int rp = gbase[b] + ((t == 0) ? 0 : sd[t - 1]);
  cursor[t] = rp;
  int node = b * 256 + t;
  if (node < N) {
    int d = cnt[t];
    dis[node] = (d > 0) ? rsqrtf((float)d) : 0.f;
    rowptr[node] = rp;
  }
  __syncthreads();
  for (int j = t; j < n; j += 256) {
    unsigned v = rec[j];
    int pos = atomicAdd(&cursor[v >> 17], 1);
    srcs[pos] = (int)(v & 0x1FFFF);
  }
}

// ---- gemm1 (MFMA f16): Y[N][64] = (X[N][128] @ W[64][128]^T) * dis, fp16 out
__launch_bounds__(256)
__global__ void k_gemm1_mfma(const float* __restrict__ X, const float* __restrict__ W,
                             const float* __restrict__ dis, __half* __restrict__ Y, int N) {
  __shared__ _Float16 xl[128 * 128];   // 32 KB
  __shared__ _Float16 wl[64 * 128];    // 16 KB
  const int t = threadIdx.x;
  const int row0 = blockIdx.x * 128;

  {
    int n = t >> 2, kb = (t & 3) * 32;
    const float* src = W + n * 128 + kb;
    #pragma unroll
    for (int j = 0; j < 4; ++j) {
      float4 va = *(const float4*)&src[j * 8];
      float4 vb = *(const float4*)&src[j * 8 + 4];
      _Float16 h8[8] = {(_Float16)va.x, (_Float16)va.y, (_Float16)va.z, (_Float16)va.w,
                        (_Float16)vb.x, (_Float16)vb.y, (_Float16)vb.z, (_Float16)vb.w};
      int k = kb + j * 8;
      *(float4*)&wl[n * 128 + (k ^ ((n & 7) * 8))] = *(float4*)h8;
    }
  }
  {
    int r = t >> 1, kb = (t & 1) * 64;
    int row = row0 + r;
    #pragma unroll
    for (int j = 0; j < 8; ++j) {
      float4 va = make_float4(0.f, 0.f, 0.f, 0.f), vb = va;
      if (row < N) {
        va = *(const float4*)&X[(size_t)row * 128 + kb + j * 8];
        vb = *(const float4*)&X[(size_t)row * 128 + kb + j * 8 + 4];
      }
      _Float16 h8[8] = {(_Float16)va.x, (_Float16)va.y, (_Float16)va.z, (_Float16)va.w,
                        (_Float16)vb.x, (_Float16)vb.y, (_Float16)vb.z, (_Float16)vb.w};
      int k = kb + j * 8;
      *(float4*)&xl[r * 128 + (k ^ ((r & 7) * 8))] = *(float4*)h8;
    }
  }
  __syncthreads();

  const int w = t >> 6, l = t & 63;
  const int m0 = w * 32;
  const int lr = l & 15, q = l >> 4;

  float4v acc[2][4] = {};
  #pragma unroll
  for (int kc = 0; kc < 4; ++kc) {
    half8v a[2], b[4];
    #pragma unroll
    for (int mt = 0; mt < 2; ++mt) {
      int m = m0 + mt * 16 + lr;
      int k = (kc * 32 + q * 8) ^ ((m & 7) * 8);
      a[mt] = *(half8v*)&xl[m * 128 + k];
    }
    #pragma unroll
    for (int nt = 0; nt < 4; ++nt) {
      int n = nt * 16 + lr;
      int k = (kc * 32 + q * 8) ^ ((n & 7) * 8);
      b[nt] = *(half8v*)&wl[n * 128 + k];
    }
    #pragma unroll
    for (int mt = 0; mt < 2; ++mt)
      #pragma unroll
      for (int nt = 0; nt < 4; ++nt)
        acc[mt][nt] = __builtin_amdgcn_mfma_f32_16x16x32_f16(a[mt], b[nt], acc[mt][nt], 0, 0, 0);
  }

  #pragma unroll
  for (int mt = 0; mt < 2; ++mt) {
    #pragma unroll
    for (int r = 0; r < 4; ++r) {
      int row = row0 + m0 + mt * 16 + q * 4 + r;
      if (row < N) {
        float dr = dis[row];
        #pragma unroll
        for (int nt = 0; nt < 4; ++nt)
          Y[(size_t)row * 64 + nt * 16 + lr] = __float2half_rn(acc[mt][nt][r] * dr);
      }
    }
  }
}

// ---- gemm2 (VALU): [N][40] = (h1b[N][64] @ W2[40][64]^T) * dis ->
//      split compact halves h2a = cols 0..19, h2b = cols 20..39 (fp16) ----
__launch_bounds__(128)
__global__ void k_gemm2(const __half* __restrict__ Xh, const float* __restrict__ W,
                        const float* __restrict__ dis, __half* __restrict__ h2a,
                        __half* __restrict__ h2b, int N) {
  constexpr int KFULL = 64, MREAL = 40, BM = 128, BK = 32;
  __shared__ float xs[BM * BK];
  __shared__ float wt[BK * 64];
  const int tid = threadIdx.x;
  const int tr = tid >> 3;
  const int tc = tid & 7;
  const int row0 = blockIdx.x * BM;
  const int c0 = tc * 8;

  float4 acc[8][2];
  #pragma unroll
  for (int i = 0; i < 8; ++i) {
    acc[i][0] = make_float4(0.f, 0.f, 0.f, 0.f);
    acc[i][1] = make_float4(0.f, 0.f, 0.f, 0.f);
  }

  #pragma unroll 1
  for (int kt = 0; kt < KFULL / BK; ++kt) {
    if (kt) __syncthreads();
    #pragma unroll
    for (int j = 0; j < 8; ++j) {
      int q = tid + 128 * j;
      int r = q >> 3, kq = q & 7;
      float4 v = make_float4(0.f, 0.f, 0.f, 0.f);
      int row = row0 + r;
      if (row < N) {
        float2 raw = *(const float2*)&Xh[(size_t)row * KFULL + kt * BK + kq * 4];
        const __half* hp = (const __half*)&raw;
        v = make_float4(__half2float(hp[0]), __half2float(hp[1]),
                        __half2float(hp[2]), __half2float(hp[3]));
      }
      *(float4*)&xs[r * 32 + ((kq ^ ((r >> 3) & 7)) << 2)] = v;
    }
    #pragma unroll
    for (int j = 0; j < 4; ++j) {
      int q = tid + 128 * j;
      int c = q >> 3, kq = q & 7;
      float4 v = make_float4(0.f, 0.f, 0.f, 0.f);
      if (c < MREAL) v = *(const float4*)&W[(size_t)c * KFULL + kt * BK + kq * 4];
      wt[(kq * 4 + 0) * 64 + c] = v.x;
      wt[(kq * 4 + 1) * 64 + c] = v.y;
      wt[(kq * 4 + 2) * 64 + c] = v.z;
      wt[(kq * 4 + 3) * 64 + c] = v.w;
    }
    __syncthreads();

    #pragma unroll 2
    for (int kq = 0; kq < 8; ++kq) {
      float4 xr[8];
      #pragma unroll
      for (int i = 0; i < 8; ++i)
        xr[i] = *(const float4*)&xs[(tr * 8 + i) * 32 + ((kq ^ (tr & 7)) << 2)];
      #pragma unroll
      for (int kk = 0; kk < 4; ++kk) {
        int k = kq * 4 + kk;
        float4 w0 = *(const float4*)&wt[k * 64 + c0];
        float4 w1 = *(const float4*)&wt[k * 64 + c0 + 4];
        #pragma unroll
        for (int i = 0; i < 8; ++i) {
          float xv = ((const float*)&xr[i])[kk];
          acc[i][0].x = fmaf(xv, w0.x, acc[i][0].x);
          acc[i][0].y = fmaf(xv, w0.y, acc[i][0].y);
          acc[i][0].z = fmaf(xv, w0.z, acc[i][0].z);
          acc[i][0].w = fmaf(xv, w0.w, acc[i][0].w);
          acc[i][1].x = fmaf(xv, w1.x, acc[i][1].x);
          acc[i][1].y = fmaf(xv, w1.y, acc[i][1].y);
          acc[i][1].z = fmaf(xv, w1.z, acc[i][1].z);
          acc[i][1].w = fmaf(xv, w1.w, acc[i][1].w);
        }
      }
    }
  }

  if (c0 < MREAL) {
    #pragma unroll
    for (int i = 0; i < 8; ++i) {
      int row = row0 + tr * 8 + i;
      if (row >= N) continue;
      float dr = dis[row];
      __half hv[8];
      const float* a = (const float*)&acc[i][0];
      #pragma unroll
      for (int j = 0; j < 8; ++j) hv[j] = __float2half_rn(a[j] * dr);
      #pragma unroll
      for (int g = 0; g < 2; ++g) {
        int col4 = c0 + 4 * g;
        __half* dst = (col4 < 20) ? &h2a[(size_t)row * 20 + col4]
                                  : &h2b[(size_t)row * 20 + (col4 - 20)];
        *(float2*)dst = *(float2*)&hv[4 * g];
      }
    }
  }
}

// ---- conv1 (D=64): predicated batch-8 per half-wave (R7) ----
__launch_bounds__(256)
__global__ void k_conv64(const __half* __restrict__ H, const int* __restrict__ rowptr,
                         const int* __restrict__ srcs, const float* __restrict__ dis,
                         const float* __restrict__ bias, __half* __restrict__ out, int N) {
  int node = blockIdx.x * 4 + (threadIdx.x >> 6);
  if (node >= N) return;                 // wave-uniform
  int lane = threadIdx.x & 63;
  int sub = lane & 31, hf = lane >> 5;
  int s = rowptr[node], e = rowptr[node + 1];
  int last = e - 1;
  float ax = 0.f, ay = 0.f;
  for (int p = s + hf; p < e; p += 16) {
    int si[8];
    #pragma unroll
    for (int u = 0; u < 8; ++u) si[u] = srcs[min(p + 2 * u, last)];
    #pragma unroll
    for (int u = 0; u < 8; ++u) {
      float2 f = __half22float2(*(const __half2*)&H[(size_t)si[u] * 64 + 2 * sub]);
      if (p + 2 * u < e) { ax += f.x; ay += f.y; }
    }
  }
  ax += __shfl_xor(ax, 32);
  ay += __shfl_xor(ay, 32);
  if (hf == 0) {
    float dn = dis[node];
    float vx = fmaxf(fmaf(ax, dn, bias[2 * sub]), 0.f);
    float vy = fmaxf(fmaf(ay, dn, bias[2 * sub + 1]), 0.f);
    *(__half2*)&out[(size_t)node * 64 + 2 * sub] = __floats2half2_rn(vx, vy);
  }
}

// ---- conv2 half-pass (20 features): compact 4MB array fits one XCD L2 ----
// bias/out pre-offset by the host for the feature base of this pass.
__launch_bounds__(256)
__global__ void k_conv20(const __half* __restrict__ H, const int* __restrict__ rowptr,
                         const int* __restrict__ srcs, const float* __restrict__ dis,
                         const float* __restrict__ bias, float* __restrict__ out, int N) {
  int node = blockIdx.x * 4 + (threadIdx.x >> 6);
  if (node >= N) return;
  int lane = threadIdx.x & 63;
  int sub = lane & 31, hf = lane >> 5;
  bool act = sub < 10;                   // 10 half2 lanes cover 20 features
  int s = rowptr[node], e = rowptr[node + 1];
  int last = e - 1;
  float ax = 0.f, ay = 0.f;
  for (int p = s + hf; p < e; p += 16) {
    int si[8];
    #pragma unroll
    for (int u = 0; u < 8; ++u) si[u] = srcs[min(p + 2 * u, last)];
    #pragma unroll
    for (int u = 0; u < 8; ++u) {
      if (act) {
        float2 f = __half22float2(*(const __half2*)&H[(size_t)si[u] * 20 + 2 * sub]);
        if (p + 2 * u < e) { ax += f.x; ay += f.y; }
      }
    }
  }
  ax += __shfl_xor(ax, 32);
  ay += __shfl_xor(ay, 32);
  if (hf == 0 && act) {
    float dn = dis[node];
    float2 v = make_float2(fmaf(ax, dn, bias[2 * sub]), fmaf(ay, dn, bias[2 * sub + 1]));
    *(float2*)&out[(size_t)node * 40 + 2 * sub] = v;
  }
}

extern "C" void kernel_launch(void* const* d_in, const int* in_sizes, int n_in,
                              void* d_out, int out_size, void* d_ws, size_t ws_size,
                              hipStream_t stream) {
  const float* x  = (const float*)d_in[0];
  const int*   ed = (const int*)d_in[1];
  const float* W1 = (const float*)d_in[2];
  const float* b1 = (const float*)d_in[3];
  const float* W2 = (const float*)d_in[4];
  const float* b2 = (const float*)d_in[5];
  float* out = (float*)d_out;

  const int FIN = 128, FH = 64, FO = 40;
  const int N = in_sizes[0] / FIN;
  const int E = in_sizes[1] / 2;
  const int NBINS = (N + 255) >> 8;              // 391

  char* ws = (char*)d_ws;
  size_t off = 0;
  auto alloc = [&](size_t bytes) {
    void* p = ws + off;
    off = (off + bytes + 255) & ~(size_t)255;
    return p;
  };
  int*    flag    = (int*)alloc(4);
  int*    gbincnt = (int*)alloc(512 * 4);
  int*    gbase   = (int*)alloc(512 * 4);
  float*  dis     = (float*)alloc((size_t)N * 4);
  int*    rowptr  = (int*)alloc(((size_t)N + 1) * 4);
  int*    srcs    = (int*)alloc((size_t)E * 4);
  __half* h1      = (__half*)alloc((size_t)N * FH * 2);   // gemm1 out; aliases binbuf
  __half* h1b     = (__half*)alloc((size_t)N * FH * 2);   // conv1 out
  __half* h2a     = (__half*)alloc((size_t)N * 20 * 2);   // gemm2 cols 0..19 (4MB)
  __half* h2b     = (__half*)alloc((size_t)N * 20 * 2);   // gemm2 cols 20..39 (4MB)
  int cap = (int)(((size_t)N * FH * 2) / ((size_t)NBINS * 4));
  if (cap > 8192) cap = 8192;                    // mean bin load ~4092
  unsigned* binbuf = (unsigned*)h1;              // dead before gemm1 writes h1

  hipMemsetAsync(gbincnt, 0, 512 * 4, stream);
  k_detect<<<1, 256, 0, stream>>>(ed, flag, in_sizes[1]);

  int fb = (E + 4095) / 4096;
  k_binfill<<<fb, 256, 0, stream>>>(ed, flag, gbincnt, binbuf, E, cap);
  k_binscan<<<1, 256, 0, stream>>>(gbincnt, gbase, rowptr, NBINS, N, cap);
  k_degscat<<<NBINS, 256, 0, stream>>>(binbuf, gbincnt, gbase, dis, rowptr, srcs, N, cap);

  int mb = (N + 127) / 128;
  int cb = (N + 3) / 4;
  k_gemm1_mfma<<<mb, 256, 0, stream>>>(x, W1, dis, h1, N);
  k_conv64<<<cb, 256, 0, stream>>>(h1, rowptr, srcs, dis, b1, h1b, N);
  k_gemm2<<<mb, 128, 0, stream>>>(h1b, W2, dis, h2a, h2b, N);
  k_conv20<<<cb, 256, 0, stream>>>(h2a, rowptr, srcs, dis, b2, out, N);
  k_conv20<<<cb, 256, 0, stream>>>(h2b, rowptr, srcs, dis, b2 + 20, out + 20, N);
}